// Round 9
// baseline (405.292 us; speedup 1.0000x reference)
//
#include <hip/hip_runtime.h>
#include <hip/hip_bf16.h>

// ---------------------------------------------------------------------------
// MoE dense all-expert forward, MI355X / gfx950.  B=16384, D=H=O=256, E=32.
// Round 9: 2 blocks/CU co-residency + 32x32x16 MFMA.
//  - 512 blocks x 512 thr: block = 64 rows x 16 experts (eg half)
//  - LDS/block ~69 KB, regs/wave ~118 -> 2 blocks/CU (16 waves/CU TLP)
//  - mfma_f32_32x32x16_bf16: acc 64 regs, 4x fewer matrix instrs
//  - crews: waves 0-3 GEMM1(e) / waves 4-7 GEMM2(e-1); lgkm-only barriers
//  - perfect LDS swizzle SW(r,c)=c^(r&31): conflict-free b128 reads/writes
//  - distance-2 ping-pong weight prefetch, parity-selected (no v_mov rotate)
// ---------------------------------------------------------------------------

typedef __attribute__((ext_vector_type(8)))  short bf16x8;   // 8 bf16
typedef __attribute__((ext_vector_type(16))) float f32x16;   // 32x32 acc
typedef __attribute__((ext_vector_type(4)))  float f32x4;

__device__ __forceinline__ unsigned short f2bf(float f) {
    unsigned u = __builtin_bit_cast(unsigned, f);
    u += 0x7FFFu + ((u >> 16) & 1u);        // round-to-nearest-even
    return (unsigned short)(u >> 16);
}
__device__ __forceinline__ unsigned pack_bf16x2(float a, float b) {
    return (unsigned)f2bf(a) | ((unsigned)f2bf(b) << 16);
}

// barrier that waits only LDS (lgkmcnt), leaving global prefetches in flight
__device__ __forceinline__ void lds_barrier() {
    asm volatile("s_waitcnt lgkmcnt(0)\n\ts_barrier" ::: "memory");
}

// perfect swizzle for [64 rows][256 elem] bf16 tiles: chunk c in 0..31
#define SW(r, c) (((c) ^ ((r) & 31)))
#define LADDR(r, c) (((r) << 8) + (SW(r, c) << 3))   // ushort index of 16B chunk

// ------------------- W f32 -> bf16 convert + tile reorder ------------------
// chunk c = (((e*2 + ph)*4 + g)*16 + ks)*2 + mt  (512 ushorts = 1 KB each).
// Lane-slot l (0..63), j (0..7): W row = g*64 + mt*32 + (l&31),
//                                k     = ks*16 + (l>>5)*8 + j
// == the mfma_32x32x16 A-frag order; consuming lane l reads chunk + l*8.
__global__ __launch_bounds__(256) void cvt_w(const float* __restrict__ W1,
                                             const float* __restrict__ W2,
                                             unsigned short* __restrict__ Wr) {
    int T = blockIdx.x * 256 + threadIdx.x;          // 524288 threads
    int l = T & 63, c = T >> 6;
    int mt = c & 1, ks = (c >> 1) & 15, g = (c >> 5) & 3;
    int ph = (c >> 7) & 1, e = c >> 8;
    int row = g * 64 + mt * 32 + (l & 31);
    int k0  = ks * 16 + (l >> 5) * 8;
    const float* src = ((ph == 0) ? W1 : W2) + ((long)e * 256 + row) * 256 + k0;
    float4 v0 = ((const float4*)src)[0], v1 = ((const float4*)src)[1];
    uint4 o;
    o.x = pack_bf16x2(v0.x, v0.y); o.y = pack_bf16x2(v0.z, v0.w);
    o.z = pack_bf16x2(v1.x, v1.y); o.w = pack_bf16x2(v1.z, v1.w);
    *(uint4*)(Wr + (long)c * 512 + l * 8) = o;
}

// ------------------------------ fused MoE ----------------------------------
// 512 blocks x 512 thr (2 blocks/CU). Block = (rg of 64 rows) x (eg half).
__global__ __launch_bounds__(512, 2) void moe_kernel(
    const float* __restrict__ x,
    const unsigned short* __restrict__ Wr,
    const float* __restrict__ bias1,
    const float* __restrict__ b2,
    const float* __restrict__ Wg,
    const float* __restrict__ bg,
    float* __restrict__ out,
    float* __restrict__ part1)
{
    __shared__ __align__(16) unsigned short x_s[64 * 256];   // 32 KB
    __shared__ __align__(16) unsigned short h_s[64 * 256];   // 32 KB
    __shared__ float gws[64 * 17];                           // 4.25 KB

    const int tid  = threadIdx.x;
    const int wv   = tid >> 6, lane = tid & 63;
    const int l31  = lane & 31, hi = lane >> 5;
    const int crew = wv >> 2, g = wv & 3;       // crew0 = GEMM1, crew1 = GEMM2
    const int eg   = blockIdx.x & 1;            // expert half
    const int rg   = blockIdx.x >> 1;
    const int row0 = rg * 64;
    const int ebase = eg * 16;

    // ---- stage x tile: f32 global -> bf16 LDS (swizzled) ----
#pragma unroll
    for (int it = 0; it < 4; ++it) {
        int chunk = tid + it * 512;             // 2048 chunks of 8 elems
        int r = chunk >> 5, c = chunk & 31;
        const float4* s = (const float4*)(x + (long)(row0 + r) * 256 + c * 8);
        float4 v0 = s[0], v1 = s[1];
        uint4 o;
        o.x = pack_bf16x2(v0.x, v0.y); o.y = pack_bf16x2(v0.z, v0.w);
        o.z = pack_bf16x2(v1.x, v1.y); o.w = pack_bf16x2(v1.z, v1.w);
        *(uint4*)(&x_s[LADDR(r, c)]) = o;
    }

    // ---- inline gating: 8 rows per wave, all f32 (matches reference) ----
    {
        const int e32 = lane & 31, half = lane >> 5;
        const float4* wg4 = (const float4*)(Wg + e32 * 256 + half * 128);
        float bgv = bg[e32];
        for (int i = 0; i < 8; ++i) {
            int lr = wv * 8 + i;
            const float4* xr4 = (const float4*)(x + (long)(row0 + lr) * 256 + half * 128);
            float a0 = 0.f;
#pragma unroll
            for (int tt = 0; tt < 32; ++tt) {
                float4 w = wg4[tt], xv = xr4[tt];
                a0 = fmaf(w.x, xv.x, a0); a0 = fmaf(w.y, xv.y, a0);
                a0 = fmaf(w.z, xv.z, a0); a0 = fmaf(w.w, xv.w, a0);
            }
            a0 += __shfl_xor(a0, 32);
            float score = (a0 + bgv) / 2.71828182845904523f;    // TEMP = e

            float m = score;
#pragma unroll
            for (int d = 16; d >= 1; d >>= 1) m = fmaxf(m, __shfl_xor(m, d));
            float p = expf(score - m);
            float ps = p;
#pragma unroll
            for (int d = 16; d >= 1; d >>= 1) ps += __shfl_xor(ps, d);
            float prob = p / ps;

            int rank = 0;
#pragma unroll
            for (int j = 0; j < 32; ++j) {
                float pj = __shfl(prob, j);
                rank += (pj > prob || (pj == prob && j < e32)) ? 1 : 0;
            }
            float kept = (rank < 22) ? prob : 0.f;
            float wsum = kept;
#pragma unroll
            for (int d = 16; d >= 1; d >>= 1) wsum += __shfl_xor(wsum, d);
            float weight = kept / (wsum + 1e-8f);

            if (half == 0 && (e32 >> 4) == eg)
                gws[lr * 17 + (e32 & 15)] = weight;
        }
    }

    lds_barrier();   // x_s + gws ready

    // ---- accumulators: crew0 per-expert hacc, crew1 persistent out acc ----
    f32x16 acc[2][2];                           // [mt][nt] = 64 regs
    if (crew == 1) {
#pragma unroll
        for (int mt = 0; mt < 2; ++mt)
#pragma unroll
            for (int nt = 0; nt < 2; ++nt)
#pragma unroll
                for (int q = 0; q < 16; ++q) acc[mt][nt][q] = 0.f;
        for (int ee = 0; ee < 16; ++ee) {
            float gv0 = gws[l31 * 17 + ee];
            float gv1 = gws[(32 + l31) * 17 + ee];
#pragma unroll
            for (int mt = 0; mt < 2; ++mt)
#pragma unroll
                for (int gi = 0; gi < 4; ++gi) {
                    float4 bb = *(const float4*)(b2 + (ebase + ee) * 256 +
                                 g * 64 + mt * 32 + gi * 8 + 4 * hi);
#pragma unroll
                    for (int q = 0; q < 4; ++q) {
                        float bv = (q == 0) ? bb.x : (q == 1) ? bb.y : (q == 2) ? bb.z : bb.w;
                        acc[mt][0][gi * 4 + q] = fmaf(gv0, bv, acc[mt][0][gi * 4 + q]);
                        acc[mt][1][gi * 4 + q] = fmaf(gv1, bv, acc[mt][1][gi * 4 + q]);
                    }
                }
        }
    }

    // ---- weight stream base: (e=ebase, ph=crew, g); expert stride 131072 ----
    const unsigned short* wb = Wr + (((long)ebase * 2 + crew) * 4 + g) * 16384;

    // distance-2 ping-pong preload (ks = 0, 1 of first consumed expert)
    bf16x8 q0[2], q1[2];
#pragma unroll
    for (int mt = 0; mt < 2; ++mt) {
        q0[mt] = *(const bf16x8*)(wb + mt * 512 + lane * 8);
        q1[mt] = *(const bf16x8*)(wb + 1024 + mt * 512 + lane * 8);
    }

    // ---- expert pipeline: crew0 computes e, crew1 computes e-1 ----
#pragma unroll 1
    for (int e = 0; e <= 16; ++e) {
        if (crew == 0) {
            if (e < 16) {
#pragma unroll
                for (int mt = 0; mt < 2; ++mt)
#pragma unroll
                    for (int nt = 0; nt < 2; ++nt)
#pragma unroll
                        for (int q = 0; q < 16; ++q) acc[mt][nt][q] = 0.f;
                const unsigned short* wc = wb + (long)e * 131072;
#pragma unroll
                for (int ks = 0; ks < 16; ++ks) {
                    bf16x8 bx0 = *(const bf16x8*)(&x_s[LADDR(l31, ks * 2 + hi)]);
                    bf16x8 bx1 = *(const bf16x8*)(&x_s[LADDR(32 + l31, ks * 2 + hi)]);
                    bf16x8 a0 = (ks & 1) ? q1[0] : q0[0];
                    bf16x8 a1 = (ks & 1) ? q1[1] : q0[1];
                    acc[0][0] = __builtin_amdgcn_mfma_f32_32x32x16_bf16(a0, bx0, acc[0][0], 0, 0, 0);
                    acc[0][1] = __builtin_amdgcn_mfma_f32_32x32x16_bf16(a0, bx1, acc[0][1], 0, 0, 0);
                    acc[1][0] = __builtin_amdgcn_mfma_f32_32x32x16_bf16(a1, bx0, acc[1][0], 0, 0, 0);
                    acc[1][1] = __builtin_amdgcn_mfma_f32_32x32x16_bf16(a1, bx1, acc[1][1], 0, 0, 0);
                    const unsigned short* pf = (ks < 14)
                        ? (wc + (ks + 2) * 1024)
                        : (wc + 131072 + (ks - 14) * 1024);
                    if (ks & 1) {
#pragma unroll
                        for (int mt = 0; mt < 2; ++mt)
                            q1[mt] = *(const bf16x8*)(pf + mt * 512 + lane * 8);
                    } else {
#pragma unroll
                        for (int mt = 0; mt < 2; ++mt)
                            q0[mt] = *(const bf16x8*)(pf + mt * 512 + lane * 8);
                    }
                }
            }
        } else {
            if (e >= 1) {
                const unsigned short* wc = wb + (long)(e - 1) * 131072;
#pragma unroll
                for (int ks = 0; ks < 16; ++ks) {
                    bf16x8 bh0 = *(const bf16x8*)(&h_s[LADDR(l31, ks * 2 + hi)]);
                    bf16x8 bh1 = *(const bf16x8*)(&h_s[LADDR(32 + l31, ks * 2 + hi)]);
                    bf16x8 a0 = (ks & 1) ? q1[0] : q0[0];
                    bf16x8 a1 = (ks & 1) ? q1[1] : q0[1];
                    acc[0][0] = __builtin_amdgcn_mfma_f32_32x32x16_bf16(a0, bh0, acc[0][0], 0, 0, 0);
                    acc[0][1] = __builtin_amdgcn_mfma_f32_32x32x16_bf16(a0, bh1, acc[0][1], 0, 0, 0);
                    acc[1][0] = __builtin_amdgcn_mfma_f32_32x32x16_bf16(a1, bh0, acc[1][0], 0, 0, 0);
                    acc[1][1] = __builtin_amdgcn_mfma_f32_32x32x16_bf16(a1, bh1, acc[1][1], 0, 0, 0);
                    const unsigned short* pf = (ks < 14)
                        ? (wc + (ks + 2) * 1024)
                        : (wc + 131072 + (ks - 14) * 1024);
                    if (ks & 1) {
#pragma unroll
                        for (int mt = 0; mt < 2; ++mt)
                            q1[mt] = *(const bf16x8*)(pf + mt * 512 + lane * 8);
                    } else {
#pragma unroll
                        for (int mt = 0; mt < 2; ++mt)
                            q0[mt] = *(const bf16x8*)(pf + mt * 512 + lane * 8);
                    }
                }
            }
        }

        lds_barrier();   // crew1 done reading h_s(e-1); crew0 acc(e) ready

        if (crew == 0 && e < 16) {
            // epilogue: +b1, relu, * gate weight, conflict-free uint2 -> h_s
            float gw0 = gws[l31 * 17 + e];
            float gw1 = gws[(32 + l31) * 17 + e];
#pragma unroll
            for (int mt = 0; mt < 2; ++mt)
#pragma unroll
                for (int gi = 0; gi < 4; ++gi) {
                    float4 bb = *(const float4*)(bias1 + (ebase + e) * 256 +
                                 g * 64 + mt * 32 + gi * 8 + 4 * hi);
                    int c = g * 8 + mt * 4 + gi;        // H chunk index
#pragma unroll
                    for (int nt = 0; nt < 2; ++nt) {
                        int r = nt * 32 + l31;
                        float gw = nt ? gw1 : gw0;
                        float v0 = fmaxf(acc[mt][nt][gi * 4 + 0] + bb.x, 0.f) * gw;
                        float v1 = fmaxf(acc[mt][nt][gi * 4 + 1] + bb.y, 0.f) * gw;
                        float v2 = fmaxf(acc[mt][nt][gi * 4 + 2] + bb.z, 0.f) * gw;
                        float v3 = fmaxf(acc[mt][nt][gi * 4 + 3] + bb.w, 0.f) * gw;
                        uint2 p;
                        p.x = pack_bf16x2(v0, v1);
                        p.y = pack_bf16x2(v2, v3);
                        *(uint2*)(&h_s[LADDR(r, c) + 4 * hi]) = p;
                    }
                }
        }

        lds_barrier();   // h_s(e) final, visible to crew1 next phase
    }

    // ---- final store: crew1 out acc -> out (eg=0) or partial (eg=1) ----
    if (crew == 1) {
        float* po = ((eg == 0) ? out : part1) + (long)row0 * 256;
#pragma unroll
        for (int mt = 0; mt < 2; ++mt)
#pragma unroll
            for (int nt = 0; nt < 2; ++nt)
#pragma unroll
                for (int gi = 0; gi < 4; ++gi) {
                    f32x4 v;
#pragma unroll
                    for (int q = 0; q < 4; ++q) v[q] = acc[mt][nt][gi * 4 + q];
                    *(f32x4*)(po + (long)(nt * 32 + l31) * 256 +
                              g * 64 + mt * 32 + gi * 8 + 4 * hi) = v;
                }
    }
}

// ------------------------------ combine ------------------------------------
__global__ __launch_bounds__(256) void combine(const float* __restrict__ p1,
                                               float* __restrict__ out) {
    int i = blockIdx.x * 256 + threadIdx.x;     // 1M float4
    float4 a = ((const float4*)out)[i];
    float4 b = ((const float4*)p1)[i];
    a.x += b.x; a.y += b.y; a.z += b.z; a.w += b.w;
    ((float4*)out)[i] = a;
}

// ------------------------------- launch ------------------------------------
extern "C" void kernel_launch(void* const* d_in, const int* in_sizes, int n_in,
                              void* d_out, int out_size, void* d_ws, size_t ws_size,
                              hipStream_t stream) {
    (void)in_sizes; (void)n_in; (void)out_size; (void)ws_size;
    const float* x  = (const float*)d_in[0];   // [16384,256]
    const float* W1 = (const float*)d_in[1];   // [32,256,256]
    const float* b1 = (const float*)d_in[2];   // [32,256]
    const float* W2 = (const float*)d_in[3];   // [32,256,256]
    const float* b2 = (const float*)d_in[4];   // [32,256]
    const float* Wg = (const float*)d_in[5];   // [32,256]
    const float* bg = (const float*)d_in[6];   // [32]
    float* out = (float*)d_out;                // [16384,256]

    // ws: Wr 8 MB (+256 KB prefetch-overrun pad) at 0; part1 16 MB at 16 MB.
    unsigned short* Wr    = (unsigned short*)d_ws;
    float*          part1 = (float*)((char*)d_ws + (16u << 20));

    cvt_w<<<2048, 256, 0, stream>>>(W1, W2, Wr);
    moe_kernel<<<512, 512, 0, stream>>>(x, Wr, b1, b2, Wg, bg, out, part1);
    combine<<<4096, 256, 0, stream>>>(part1, out);
}